// Round 10
// baseline (148.195 us; speedup 1.0000x reference)
//
#include <hip/hip_runtime.h>

#define NEV 256   // events
#define NP  512   // particles per event
#define HD  16    // hidden dim
#define KBW 40    // kb row stride (dwords): 32 key slots + 8 pad
#define GBW 36    // gb row stride (floats): gg[0..16) bb[16..32) + 4 pad

// manual LDS layout (bytes)
#define KB_OFF 0          // u32 kb[512][KBW]            = 81920
#define FH_OFF 81920      // s16x8 fragH[16][64]         = 16384
#define FL_OFF 98304      // s16x8 fragL[16][64]         = 16384
#define SQ_OFF 114688     // float sSq[512]              = 2048
#define RM_OFF 116736     // float sRedM[16]             = 64
#define W_OFF  116800     // float weights[1057]         = 4228 -> 121028 total
#define SMEM_BYTES 121040
// edge phase: float gb[512][GBW] = 73728 overlays kb (81920) only.

// weight sub-offsets (floats, from W_OFF)
#define O_W1 0
#define O_B1 64
#define O_W2 80
#define O_B2 336
#define O_WCB 352
#define O_WCD 608
#define O_BC 864
#define O_WO1 880
#define O_BO1 1008
#define O_WO2 1016
#define O_BO2 1048
#define O_WO3 1052
#define O_BO3 1056

typedef short s16x8  __attribute__((ext_vector_type(8)));
typedef float f32x16 __attribute__((ext_vector_type(16)));

#define Z16 {0.f,0.f,0.f,0.f,0.f,0.f,0.f,0.f,0.f,0.f,0.f,0.f,0.f,0.f,0.f,0.f}

__device__ __forceinline__ float elu_f(float x) {
    return x > 0.0f ? x : (__expf(x) - 1.0f);
}
__device__ __forceinline__ unsigned umin_(unsigned a, unsigned b) { return a < b ? a : b; }
__device__ __forceinline__ unsigned med3u(unsigned a, unsigned b, unsigned c) {
    unsigned d;
    asm("v_med3_u32 %0, %1, %2, %3" : "=v"(d) : "v"(a), "v"(b), "v"(c));
    return d;
}
__device__ __forceinline__ unsigned short rneb(float f) {   // f32 -> bf16 bits RNE
    unsigned u = __float_as_uint(f);
    return (unsigned short)((u + 0x7FFFu + ((u >> 16) & 1u)) >> 16);
}
__device__ __forceinline__ float bits2f(unsigned short b) {
    return __uint_as_float(((unsigned)b) << 16);
}
__device__ __forceinline__ unsigned sx32(unsigned v) {      // partner lane (l^32)
    return (unsigned)__shfl_xor((int)v, 32, 64);
}

__global__ __launch_bounds__(1024, 4) void suep_fused(
    const float* __restrict__ x_pf,
    const float* __restrict__ W1,  const float* __restrict__ b1,
    const float* __restrict__ W2,  const float* __restrict__ b2,
    const float* __restrict__ Wc,  const float* __restrict__ bc,
    const float* __restrict__ Wo1, const float* __restrict__ bo1,
    const float* __restrict__ Wo2, const float* __restrict__ bo2,
    const float* __restrict__ Wo3, const float* __restrict__ bo3,
    float* __restrict__ out)
{
    __shared__ __align__(16) unsigned char smem[SMEM_BYTES];

    unsigned* kb       = (unsigned*)(smem + KB_OFF);
    s16x8 (*fragH)[64] = (s16x8(*)[64])(smem + FH_OFF);
    s16x8 (*fragL)[64] = (s16x8(*)[64])(smem + FL_OFF);
    float* gbase       = (float*)(smem + KB_OFF);        // edge-phase overlay
    float* sSq         = (float*)(smem + SQ_OFF);
    float* sRedM       = (float*)(smem + RM_OFF);
    float* sW          = (float*)(smem + W_OFF);
    float (*sRed)[HD]  = (float(*)[HD])(smem + W_OFF);   // overlays dead encoder wts
    float* sPool       = sW + 256;                       // inside dead W2 region

    const int tid = threadIdx.x, ev = blockIdx.x;
    const int l  = tid & 63;
    const int w  = tid >> 6;          // wave 0..15, owns rows [32w, 32w+32)
    const int rl = l & 31;            // row-in-tile AND acc col-lane
    const int kh = l >> 5;            // half role (hi/lo frag build, scan halves)
    const int r  = 32 * w + rl;       // this lane's row/node

    // ---- stage weights ----
    if (tid < 64)  sW[O_W1 + tid] = W1[tid];
    if (tid < HD)  { sW[O_B1+tid] = b1[tid]; sW[O_B2+tid] = b2[tid]; sW[O_BC+tid] = bc[tid]; }
    if (tid < 256) {
        sW[O_W2 + tid] = W2[tid];
        float wb = Wc[256 + tid];
        sW[O_WCB + tid] = wb;
        sW[O_WCD + tid] = Wc[tid] - wb;
    }
    if (tid < 128) sW[O_WO1 + tid] = Wo1[tid];
    if (tid < 8)   sW[O_BO1 + tid] = bo1[tid];
    if (tid < 32)  sW[O_WO2 + tid] = Wo2[tid];
    if (tid < 4)   { sW[O_BO2+tid] = bo2[tid]; sW[O_WO3+tid] = Wo3[tid]; }
    if (tid == 0)  sW[O_BO3] = bo3[0];
    __syncthreads();

    // ---- encoder: h[r] (kh halves duplicate) ----
    float hr[HD];
    {
        float4 xv = ((const float4*)x_pf)[ev * NP + r];
        float e1[HD];
#pragma unroll
        for (int c = 0; c < HD; ++c) {
            float a = sW[O_B1 + c];
            a = fmaf(xv.x, sW[O_W1 + 0*HD + c], a);
            a = fmaf(xv.y, sW[O_W1 + 1*HD + c], a);
            a = fmaf(xv.z, sW[O_W1 + 2*HD + c], a);
            a = fmaf(xv.w, sW[O_W1 + 3*HD + c], a);
            e1[c] = elu_f(a);
        }
#pragma unroll
        for (int c = 0; c < HD; ++c) {
            float a = sW[O_B2 + c];
#pragma unroll
            for (int f = 0; f < HD; ++f) a = fmaf(e1[f], sW[O_W2 + f*HD + c], a);
            hr[c] = elu_f(a);
        }
    }

    // slot swizzle: key for col c of row rr lives at slot c ^ ((rr>>3)&3).
    // scan read pointers (row r, half kh), loop/conv-invariant:
    const int rho = (rl >> 3) & 3;    // (r>>3)&3 == (rl>>3)&3 since 32w % 32 == 0
    const uint2* rp0 = (const uint2*)&kb[r*KBW + (((16*kh +  0) ^ rho) & ~1)];
    const uint2* rp1 = (const uint2*)&kb[r*KBW + (((16*kh +  2) ^ rho) & ~1)];
    const uint2* rp2 = (const uint2*)&kb[r*KBW + (((16*kh +  4) ^ rho) & ~1)];
    const uint2* rp3 = (const uint2*)&kb[r*KBW + (((16*kh +  6) ^ rho) & ~1)];
    const uint2* rp4 = (const uint2*)&kb[r*KBW + (((16*kh +  8) ^ rho) & ~1)];
    const uint2* rp5 = (const uint2*)&kb[r*KBW + (((16*kh + 10) ^ rho) & ~1)];
    const uint2* rp6 = (const uint2*)&kb[r*KBW + (((16*kh + 12) ^ rho) & ~1)];
    const uint2* rp7 = (const uint2*)&kb[r*KBW + (((16*kh + 14) ^ rho) & ~1)];
    // store pointers: acc q-group g -> rows (32w+4kh+8g)+(q&3), slot rl^g
    unsigned* wg0 = &kb[(32*w + 4*kh +  0)*KBW + (rl ^ 0)];
    unsigned* wg1 = &kb[(32*w + 4*kh +  8)*KBW + (rl ^ 1)];
    unsigned* wg2 = &kb[(32*w + 4*kh + 16)*KBW + (rl ^ 2)];
    unsigned* wg3 = &kb[(32*w + 4*kh + 24)*KBW + (rl ^ 3)];

    // ---- one DynamicEdgeConv; hr (regs) -> hr/pool (regs) ----
    auto do_conv = [&](bool last) {
        __syncthreads();     // BAR-D: previous phase's LDS reads all done

        // build frags: kh=0 writes hi + sq, kh=1 writes lo
        {
            s16x8 v0, v1;
            float sq = 0.0f;
#pragma unroll
            for (int k = 0; k < HD; ++k) {
                unsigned short hb = rneb(hr[k]);
                float fh = bits2f(hb);
                unsigned short lb = rneb(hr[k] - fh);
                float ht = fh + bits2f(lb);
                sq = fmaf(ht, ht, sq);
                unsigned short vb = kh ? lb : hb;
                if (k < 8) v0[k] = (short)vb; else v1[k-8] = (short)vb;
            }
            s16x8 (*fr)[64] = kh ? fragL : fragH;
            fr[w][rl]      = v0;
            fr[w][rl + 32] = v1;
            if (kh == 0) sSq[r] = sq;
            float m = sq;
#pragma unroll
            for (int d = 32; d >= 1; d >>= 1) m = fmaxf(m, __shfl_xor(m, d, 64));
            if (l == 0) sRedM[w] = m;
        }
        __syncthreads();     // BAR-A: frags + sSq + sRedM published
        float Cv = sRedM[0];
#pragma unroll
        for (int i = 1; i < 16; ++i) Cv = fmaxf(Cv, sRedM[i]);
        Cv += 1.0f;

        s16x8 Ah = fragH[w][l], Al = fragL[w][l];   // strip-invariant A frags

        // G-tile rows [32w,32w+32) x cols [32s,32s+32):
        // G = Hh.Hh^T + Hh.Hl^T + Hl.Hh^T  (rel err ~2^-17)
        auto mm3 = [&](int s) -> f32x16 {
            s16x8 Bh = fragH[s][l], Bl = fragL[s][l];
            f32x16 z = Z16;
            f32x16 a = __builtin_amdgcn_mfma_f32_32x32x16_bf16(Al, Bh, z, 0,0,0);
            a = __builtin_amdgcn_mfma_f32_32x32x16_bf16(Ah, Bl, a, 0,0,0);
            a = __builtin_amdgcn_mfma_f32_32x32x16_bf16(Ah, Bh, a, 0,0,0);
            return a;
        };
        // keys: bits(C + sq_col - 2G) & ~511 | col (row-const sq_i dropped; >0 by C)
        // acc C/D layout: col = lane&31, row = (q&3)+8*(q>>2)+4*(lane>>5)
        auto st = [&](int s, const f32x16& a) {
            float    base = Cv + sSq[32*s + rl];
            unsigned colb = (unsigned)(32*s + rl);
#pragma unroll
            for (int q = 0; q < 16; ++q) {
                unsigned kk = (__float_as_uint(fmaf(-2.0f, a[q], base)) & 0xFFFFFE00u) | colb;
                unsigned* wq = (q>>2)==0 ? wg0 : (q>>2)==1 ? wg1 : (q>>2)==2 ? wg2 : wg3;
                wq[(q & 3) * KBW] = kk;
            }
        };

        unsigned t0=~0u,t1=~0u,t2=~0u,t3=~0u,t4=~0u,t5=~0u,t6=~0u,t7=~0u;
#define INS(KEY) do { unsigned kk = (KEY);              \
        t7 = med3u(t6, kk, t7); t6 = med3u(t5, kk, t6); \
        t5 = med3u(t4, kk, t5); t4 = med3u(t3, kk, t4); \
        t3 = med3u(t2, kk, t3); t2 = med3u(t1, kk, t2); \
        t1 = med3u(t0, kk, t1); t0 = umin_(kk, t0); } while (0)
#define SCAN16 do { uint2 c0=rp0[0], c1=rp1[0], c2=rp2[0], c3=rp3[0], \
                          c4=rp4[0], c5=rp5[0], c6=rp6[0], c7=rp7[0]; \
        INS(c0.x); INS(c0.y); INS(c1.x); INS(c1.y);                   \
        INS(c2.x); INS(c2.y); INS(c3.x); INS(c3.y);                   \
        INS(c4.x); INS(c4.y); INS(c5.x); INS(c5.y);                   \
        INS(c6.x); INS(c6.y); INS(c7.x); INS(c7.y); } while (0)

        // Pipelined barrier-free strip loop (producer wave == consumer wave;
        // per-wave LDS ops execute in order, so RAW/WAR need no drains).
        // Per half-iter: MFMA(s+1) | scan(s-1) | store(s) — scan reads LDS data
        // stored one half-iter ago; MFMA result consumed one half-iter later.
        f32x16 accA = mm3(0), accB;
#pragma unroll 1
        for (int s = 0; s < 16; s += 2) {
            accB = mm3(s + 1);
            if (s > 0) SCAN16;         // strip s-1
            st(s, accA);
            if (s + 2 < 16) accA = mm3(s + 2);
            SCAN16;                    // strip s
            st(s + 1, accB);
        }
        SCAN16;                        // strip 15
#undef SCAN16
#undef INS

        // merge col-half lists: exact top-8 of two sorted-8 = half-cleaner.
        // kh=0's m0..3 = min(a_i,b_{7-i}) i=0..3; kh=1's m0..3 = the other four
        // pairs min(a_i,b_{7-i}) i=4..7 — union over the lane pair = full top-8.
        unsigned m0 = umin_(t0, sx32(t7)), m1 = umin_(t1, sx32(t6)),
                 m2 = umin_(t2, sx32(t5)), m3 = umin_(t3, sx32(t4));

        // edge MLP projections: kh=0 -> gg = h@WcB ; kh=1 -> bb = bc + h@WcD
        float gb[HD];
        {
            const float* Wm = kh ? (sW + O_WCD) : (sW + O_WCB);
#pragma unroll
            for (int c = 0; c < HD; ++c) gb[c] = kh ? sW[O_BC + c] : 0.0f;
#pragma unroll
            for (int f = 0; f < HD; ++f) {
                float hf = hr[f];
#pragma unroll
                for (int c = 0; c < HD; ++c) gb[c] = fmaf(hf, Wm[f*HD + c], gb[c]);
            }
        }
        __syncthreads();     // BAR-B: all scans done; kb region becomes gg/bb table
        {
            float4* gr = (float4*)(gbase + r*GBW + 16*kh);
            gr[0] = make_float4(gb[0],  gb[1],  gb[2],  gb[3]);
            gr[1] = make_float4(gb[4],  gb[5],  gb[6],  gb[7]);
            gr[2] = make_float4(gb[8],  gb[9],  gb[10], gb[11]);
            gr[3] = make_float4(gb[12], gb[13], gb[14], gb[15]);
        }
        __syncthreads();     // BAR-C: gg/bb published

        // gather own 4 neighbors (each kh lane holds a different half of top-8)
        int j0 = (int)(m0 & 511u), j1 = (int)(m1 & 511u);
        int j2 = (int)(m2 & 511u), j3 = (int)(m3 & 511u);
        float z[HD];
        {
            const float4* g0 = (const float4*)(gbase + j0*GBW);
            const float4* g1 = (const float4*)(gbase + j1*GBW);
            const float4* g2 = (const float4*)(gbase + j2*GBW);
            const float4* g3 = (const float4*)(gbase + j3*GBW);
#pragma unroll
            for (int qq = 0; qq < 4; ++qq) {
                float4 va = g0[qq], vb = g1[qq], vc = g2[qq], vd = g3[qq];
                z[4*qq+0] = fmaxf(fmaxf(va.x, vb.x), fmaxf(vc.x, vd.x));
                z[4*qq+1] = fmaxf(fmaxf(va.y, vb.y), fmaxf(vc.y, vd.y));
                z[4*qq+2] = fmaxf(fmaxf(va.z, vb.z), fmaxf(vc.z, vd.z));
                z[4*qq+3] = fmaxf(fmaxf(va.w, vb.w), fmaxf(vc.w, vd.w));
            }
        }
#pragma unroll
        for (int c = 0; c < HD; ++c) z[c] = fmaxf(z[c], __shfl_xor(z[c], 32, 64));

        // finalize: fo = elu(z + bb[r]) in BOTH kh lanes (2-way broadcast read)
        float fo[HD];
        {
            const float4* br = (const float4*)(gbase + r*GBW + 16);
#pragma unroll
            for (int qq = 0; qq < 4; ++qq) {
                float4 vb = br[qq];
                fo[4*qq+0] = elu_f(z[4*qq+0] + vb.x);
                fo[4*qq+1] = elu_f(z[4*qq+1] + vb.y);
                fo[4*qq+2] = elu_f(z[4*qq+2] + vb.z);
                fo[4*qq+3] = elu_f(z[4*qq+3] + vb.w);
            }
        }

        if (!last) {
#pragma unroll
            for (int c = 0; c < HD; ++c) hr[c] = fo[c];
        } else {
            // mean pool: full-wave sum counts each row twice -> /1024
#pragma unroll
            for (int d = 32; d >= 1; d >>= 1) {
#pragma unroll
                for (int c = 0; c < HD; ++c) fo[c] += __shfl_xor(fo[c], d, 64);
            }
            if (l == 0) {
                ((float4*)(&sRed[w][0]))[0] = make_float4(fo[0],  fo[1],  fo[2],  fo[3]);
                ((float4*)(&sRed[w][0]))[1] = make_float4(fo[4],  fo[5],  fo[6],  fo[7]);
                ((float4*)(&sRed[w][0]))[2] = make_float4(fo[8],  fo[9],  fo[10], fo[11]);
                ((float4*)(&sRed[w][0]))[3] = make_float4(fo[12], fo[13], fo[14], fo[15]);
            }
            __syncthreads();
            if (tid < HD) {
                float s = 0.0f;
#pragma unroll
                for (int ww = 0; ww < 16; ++ww) s += sRed[ww][tid];
                sPool[tid] = s * (1.0f / 1024.0f);
            }
            __syncthreads();
        }
    };

    do_conv(false);
    do_conv(true);

    // ---- head MLP + outputs ----
    if (tid == 0) {
        float o1[8];
#pragma unroll
        for (int c = 0; c < 8; ++c) {
            float a = sW[O_BO1 + c];
#pragma unroll
            for (int f = 0; f < HD; ++f) a = fmaf(sPool[f], sW[O_WO1 + f*8 + c], a);
            o1[c] = elu_f(a);
        }
        float o2[4];
#pragma unroll
        for (int c = 0; c < 4; ++c) {
            float a = sW[O_BO2 + c];
#pragma unroll
            for (int f = 0; f < 8; ++f) a = fmaf(o1[f], sW[O_WO2 + f*4 + c], a);
            o2[c] = elu_f(a);
        }
        float o3 = sW[O_BO3];
#pragma unroll
        for (int f = 0; f < 4; ++f) o3 = fmaf(o2[f], sW[O_WO3 + f], o3);
        out[ev] = o3;
        out[NEV + ev] = (float)ev;
    }
}

extern "C" void kernel_launch(void* const* d_in, const int* in_sizes, int n_in,
                              void* d_out, int out_size, void* d_ws, size_t ws_size,
                              hipStream_t stream) {
    const float* x_pf = (const float*)d_in[0];
    // d_in[1] = batch_pf (contiguous equal-size events; unused)
    const float* W1  = (const float*)d_in[2];
    const float* b1  = (const float*)d_in[3];
    const float* W2  = (const float*)d_in[4];
    const float* b2  = (const float*)d_in[5];
    const float* Wc  = (const float*)d_in[6];
    const float* bc  = (const float*)d_in[7];
    const float* Wo1 = (const float*)d_in[8];
    const float* bo1 = (const float*)d_in[9];
    const float* Wo2 = (const float*)d_in[10];
    const float* bo2 = (const float*)d_in[11];
    const float* Wo3 = (const float*)d_in[12];
    const float* bo3 = (const float*)d_in[13];
    float* out = (float*)d_out;

    hipLaunchKernelGGL(suep_fused, dim3(NEV), dim3(1024), 0, stream,
                       x_pf, W1, b1, W2, b2, Wc, bc,
                       Wo1, bo1, Wo2, bo2, Wo3, bo3, out);
}